// Round 11
// baseline (251.900 us; speedup 1.0000x reference)
//
#include <hip/hip_runtime.h>
#include <hip/hip_fp16.h>
#include <stdint.h>

// ============================================================================
// Mix_Loss on MI355X.  R20 (from passing R18 @225.6us BEST):
//  R19 post-mortem: dense proto failed twice (db=34) with no auditable bug ->
//  class-indexed register accumulation abandoned per pre-registration.
//  R20 = R18 with 3 structure-only folds (all bodies verbatim, no hot-loop
//  changes); 6 launches -> 3 + memset:
//   - k_flags INTO k_pq_proto head (flags logic bit-identical; dual-column
//     blockCnt write keeps k_place byte-identical; init via hipMemsetAsync).
//   - k_protoFinal INTO k_place block-0 tail (counts -> sTot).
//   - k_final INTO k_sample epilogue (R14-proven done-counter).
// ============================================================================

#define NPIX  262144   // B*H*W = 4*256*256
#define NCLS  8
#define NQ    256
#define NNEG  256
#define NBLK  1024     // 256-pixel chunks for place

typedef unsigned short u16;
typedef unsigned int   u32;

struct TFKeys { u32 k1[8][2], k2[8][2], k3[8][2]; };

// JAX threefry2x32 (20 rounds)
__host__ __device__ inline void tf2x32(u32 k0, u32 k1, u32 x0, u32 x1, u32& o0, u32& o1) {
  u32 ks2 = k0 ^ k1 ^ 0x1BD11BDAu;
  x0 += k0; x1 += k1;
#define TFR(R) { x0 += x1; x1 = (x1 << (R)) | (x1 >> (32 - (R))); x1 ^= x0; }
  TFR(13) TFR(15) TFR(26) TFR(6)
  x0 += k1;  x1 += ks2 + 1u;
  TFR(17) TFR(29) TFR(16) TFR(24)
  x0 += ks2; x1 += k0 + 2u;
  TFR(13) TFR(15) TFR(26) TFR(6)
  x0 += k0;  x1 += k1 + 3u;
  TFR(17) TFR(29) TFR(16) TFR(24)
  x0 += k1;  x1 += ks2 + 4u;
  TFR(13) TFR(15) TFR(26) TFR(6)
  x0 += ks2; x1 += k0 + 5u;
#undef TFR
  o0 = x0; o1 = x1;
}

__device__ inline float bfv(u16 v) { return __uint_as_float(((u32)v) << 16); }
__device__ inline float lo16(u32 v) { return __uint_as_float(v << 16); }
__device__ inline float hi16(u32 v) { return __uint_as_float(v & 0xFFFF0000u); }
__device__ inline float u01(u32 bits) { return __uint_as_float((bits >> 9) | 0x3F800000u) - 1.0f; }
__device__ inline u32 rbits(u32 k0, u32 k1, u32 idx) { u32 a, b; tf2x32(k0, k1, 0u, idx, a, b); return a ^ b; }
__device__ inline u32 packPQ(float p, float q) {
  return (u32)__half_as_ushort(__float2half(p)) | ((u32)__half_as_ushort(__float2half(q)) << 16);
}
__device__ inline float2 unpackPQ(u32 v) {
  return make_float2(__half2float(__ushort_as_half((u16)(v & 0xFFFFu))),
                     __half2float(__ushort_as_half((u16)(v >> 16))));
}
__device__ inline float frcp(float x) { return __builtin_amdgcn_rcpf(x); }

// ---------------------------------------------------------------------------
// R20 k_pq_proto: [flags fold (R2 logic, bit-identical)] + [R18 pq_proto body:
// LDS transpose tile + 4-way replicated pacc]. Dual-column blockCnt write so
// k_place stays byte-identical (column j = counts of 256-px chunk j).
__global__ __launch_bounds__(256) void k_pq_proto(const u16* __restrict__ mu, const u16* __restrict__ wgt,
                                                  const u16* __restrict__ sig,
                                                  const u16* __restrict__ lab, const u16* __restrict__ msk,
                                                  const u16* __restrict__ prb,
                                                  unsigned char* __restrict__ flags,
                                                  int* __restrict__ blockCnt,
                                                  u32* __restrict__ PQ, float* __restrict__ protoAcc) {
  __shared__ u32 tile[256 * 33];
  __shared__ float pacc[4 * 808];
  __shared__ int cnt[32];
  int t = threadIdx.x;
  for (int i = t; i < 4 * 808; i += 256) pacc[i] = 0.f;
  if (t < 32) cnt[t] = 0;
  __syncthreads();
  int n0 = blockIdx.x * 512;
  int b = n0 >> 16;
  int hwt = (n0 & 65535) + 2 * t;
  size_t cb = ((size_t)(b * 32)) << 16;
  // ---- flags computation (logic verbatim R2 k_flags), 2 pixels ----
  u32 mk2 = *(const u32*)(msk + (((size_t)b) << 16) + hwt);
  float mk0 = lo16(mk2), mk1 = hi16(mk2);
  int cls0 = 0, cls1 = 0; bool v0 = false, v1 = false;
  for (int s = 0; s < 8; s++) {
    u32 l2 = *(const u32*)(lab + (((size_t)(b * 8 + s)) << 16) + hwt);
    if (lo16(l2) * mk0 > 0.f) { cls0 = s; v0 = true; }
    if (hi16(l2) * mk1 > 0.f) { cls1 = s; v1 = true; }
  }
  bool h0 = false, h1 = false;
  if (v0) { float p = bfv(prb[(((size_t)(b * 8 + cls0)) << 16) + hwt]);     h0 = p < 0.97f; }
  if (v1) { float p = bfv(prb[(((size_t)(b * 8 + cls1)) << 16) + hwt + 1]); h1 = p < 0.97f; }
  {
    int half16 = (t >> 7) * 16;
    if (v0) atomicAdd(&cnt[half16 + cls0], 1);
    if (h0) atomicAdd(&cnt[half16 + 8 + cls0], 1);
    if (v1) atomicAdd(&cnt[half16 + cls1], 1);
    if (h1) atomicAdd(&cnt[half16 + 8 + cls1], 1);
    u32 f0 = (u32)cls0 | (v0 ? 16u : 0u) | (h0 ? 32u : 0u);
    u32 f1 = (u32)cls1 | (v1 ? 16u : 0u) | (h1 ? 32u : 0u);
    *(u16*)(flags + n0 + 2 * t) = (u16)(f0 | (f1 << 8));
  }
  // ---- R18 pq + proto body (uses local cls/v instead of flags re-read) ----
  int copy = (t & 3) * 808;
  int base0 = copy + cls0 * 100, base1 = copy + cls1 * 100;
  u32 m2[32];
  float ss0 = 0.f, ss1 = 0.f;
  #pragma unroll
  for (int c = 0; c < 32; c++) {
    m2[c] = *(const u32*)(mu + cb + ((size_t)c << 16) + hwt);
    float a = lo16(m2[c]), d = hi16(m2[c]);
    ss0 += a * a; ss1 += d * d;
  }
  float rn0 = 1.0f / fmaxf(sqrtf(ss0), 1e-12f);
  float rn1 = 1.0f / fmaxf(sqrtf(ss1), 1e-12f);
  u32 pk0[32], pk1[32];
  #pragma unroll
  for (int c = 0; c < 32; c++) {
    u32 w2 = *(const u32*)(wgt + cb + ((size_t)c << 16) + hwt);
    u32 s2 = *(const u32*)(sig + cb + ((size_t)c << 16) + hwt);
    float wl = lo16(w2), wh = hi16(w2);
    float sl = lo16(s2), sh = hi16(s2);
    float ml = lo16(m2[c]), mh = hi16(m2[c]);
    pk0[c] = packPQ(ml * rn0 * wl, sl * wl);
    pk1[c] = packPQ(mh * rn1 * wh, sh * wh);
    if (v0) {
      float isw = wl / sl;                       // IEEE div (matches reference)
      atomicAdd(&pacc[base0 + c * 3 + 0], isw);
      atomicAdd(&pacc[base0 + c * 3 + 1], isw * ml);
      atomicAdd(&pacc[base0 + c * 3 + 2], 1.0f / wl);
    }
    if (v1) {
      float isw = wh / sh;
      atomicAdd(&pacc[base1 + c * 3 + 0], isw);
      atomicAdd(&pacc[base1 + c * 3 + 1], isw * mh);
      atomicAdd(&pacc[base1 + c * 3 + 2], 1.0f / wh);
    }
  }
  // PQ transpose + write (verbatim R8)
  #pragma unroll
  for (int ch = 0; ch < 2; ch++) {
    if ((t >> 7) == ch) {
      int l = t & 127;
      #pragma unroll
      for (int c = 0; c < 32; c++) {
        tile[(2 * l + 0) * 33 + c] = pk0[c];
        tile[(2 * l + 1) * 33 + c] = pk1[c];
      }
    }
    __syncthreads();
    uint4* dst = (uint4*)(PQ + (size_t)(n0 + ch * 256) * 32);
    for (int k = t; k < 2048; k += 256) {
      int p = k >> 3, c4 = (k & 7) * 4;
      dst[k] = make_uint4(tile[p * 33 + c4], tile[p * 33 + c4 + 1],
                          tile[p * 33 + c4 + 2], tile[p * 33 + c4 + 3]);
    }
    __syncthreads();
  }
  // flush pacc -> protoAcc (pre-reduce 4 copies; same 768 bins)
  for (int idx = t; idx < 800; idx += 256) {
    int c8 = idx / 100, rem = idx - c8 * 100;
    if (rem < 96) {
      float sum = pacc[idx] + pacc[idx + 808] + pacc[idx + 1616] + pacc[idx + 2424];
      atomicAdd(&protoAcc[c8 * 96 + rem], sum);
    }
  }
  // blockCnt dual-column write (covers 256-px chunks 2*bid and 2*bid+1)
  if (t < 32) blockCnt[(t & 15) * NBLK + 2 * blockIdx.x + (t >> 4)] = cnt[(t >> 4) * 16 + (t & 15)];
}

// ---------------------------------------------------------------------------
// k_place (R14-proven body, byte-identical) + protoFinal tail in block 0
// (R8 body verbatim; counts reads -> block-0's own sTot).
__global__ __launch_bounds__(256) void k_place(const unsigned char* __restrict__ flags,
                                               const int* __restrict__ blockCnt,
                                               int* __restrict__ tblV, int* __restrict__ tblH,
                                               int* __restrict__ counts,
                                               const float* __restrict__ protoAcc,
                                               u32* __restrict__ protoPQ, float* __restrict__ simL,
                                               int* __restrict__ diag) {
  __shared__ int wcnt[4][16];
  __shared__ int sOff[16], sTot[16];
  __shared__ float sP[256], sQ[256];
  __shared__ int alive;
  int tid = threadIdx.x;
  int blk = blockIdx.x;
  if (tid < 16) { sOff[tid] = 0; sTot[tid] = 0; }
  __syncthreads();
  {
    int ctr = tid & 15, seg = tid >> 4;              // 16 segs x 64 entries
    const int* row = blockCnt + ctr * NBLK + seg * 64;
    int lim = blk - seg * 64;                        // j < blk  <=>  l < lim
    int pre = 0, tot = 0;
    #pragma unroll 8
    for (int l = 0; l < 64; ++l) {
      int v = row[l];
      tot += v;
      pre += (l < lim) ? v : 0;
    }
    atomicAdd(&sOff[ctr], pre);
    if (blk == 0) atomicAdd(&sTot[ctr], tot);
  }
  __syncthreads();
  if (blk == 0 && tid < 16) counts[tid] = sTot[tid];
  // ---------------- original place body ----------------
  int n = blk * 256 + tid;
  int f = flags[n];
  int cls = f & 15; bool v = (f & 16) != 0, h = (f & 32) != 0;
  int wave = tid >> 6, lane = tid & 63;
  unsigned long long below = (1ull << lane) - 1ull;
  int rv = 0, rh = 0;
  for (int s = 0; s < 8; s++) {
    unsigned long long bv = __ballot(v && (cls == s));
    unsigned long long bh = __ballot(h && (cls == s));
    if (lane == 0) { wcnt[wave][s] = __popcll(bv); wcnt[wave][8 + s] = __popcll(bh); }
    if (cls == s) { rv = __popcll(bv & below); rh = __popcll(bh & below); }
  }
  __syncthreads();
  int preV = 0, preH = 0;
  for (int w2 = 0; w2 < wave; w2++) { preV += wcnt[w2][cls]; preH += wcnt[w2][8 + cls]; }
  if (v) tblV[(size_t)cls * NPIX + sOff[cls] + preV + rv] = n;
  if (h) tblH[(size_t)cls * NPIX + sOff[8 + cls] + preH + rh] = n;
  // ---------------- protoFinal tail (block 0 only; R8 body) ----------------
  if (blk == 0) {
    if (tid == 0) alive = 0;
    float a0 = protoAcc[tid * 3 + 0], a1 = protoAcc[tid * 3 + 1], a2 = protoAcc[tid * 3 + 2];
    bool have = sTot[tid >> 5] > 0;
    bool ok = (a0 > 0.f) && (a2 > 0.f);
    __syncthreads();
    if (have && !ok) atomicOr(diag, 2);
    if (have && ok) alive = 1;
    float psig = 1.0f / a0;
    float pmu  = psig * a1;
    float pw   = 1.0f / a2;
    float sq = (have && ok) ? pmu * pmu : 0.f;
    #pragma unroll
    for (int d = 1; d < 32; d <<= 1) sq += __shfl_xor(sq, d);
    float rn = 1.0f / fmaxf(sqrtf(sq), 1e-12f);
    float pP = (have && ok) ? pmu * rn * pw : 0.f;
    float pQ = (have && ok) ? psig * pw : 0.f;
    sP[tid] = pP; sQ[tid] = pQ;
    protoPQ[tid] = packPQ(pP, pQ);
    __syncthreads();
    if (tid == 0 && alive == 0) atomicOr(diag, 32);
    if (tid < 64) {
      int i = tid >> 3, j = tid & 7;
      if (j < 7) {
        int o = (i + 1 + j) & 7;
        float acc = 0.f;
        for (int c = 0; c < 32; c++) {
          float d = sP[i * 32 + c] - sP[o * 32 + c];
          float dn = sQ[i * 32 + c] + sQ[o * 32 + c];
          acc += d * d / dn + logf(dn);
        }
        float sim = -0.5f * (acc * (1.0f / 32.0f));
        simL[i * 8 + j] = (sTot[o] > 0) ? (sim * 2.0f) : -INFINITY;  // /TEMP(0.5)
      }
    }
  }
}

// ---- R11 k_sample (proven 42.0us) + R14-proven k_final done-counter epilogue.
__global__ __launch_bounds__(256) void k_sample(TFKeys K, const float* __restrict__ simL,
                                                const int* __restrict__ counts,
                                                const int* __restrict__ tblV, const int* __restrict__ tblH,
                                                const u32* __restrict__ PQ, const u32* __restrict__ protoPQ,
                                                float* __restrict__ ceAcc, int* __restrict__ diag,
                                                int* __restrict__ doneCnt, u32* __restrict__ out) {
  __shared__ float redM[4], redS[4];
  int blk = blockIdx.x;
  int i = blk >> 8, q = blk & 255;
  int t = threadIdx.x;
  u32 abits = rbits(K.k1[i][0], K.k1[i][1], (u32)q);
  float au = u01(abits);
  int hc = counts[8 + i];
  int ra = (int)(au * (float)hc);
  int cap = hc - 1; if (cap < 0) cap = 0;
  if (ra > cap) ra = cap; if (ra < 0) ra = 0;
  int ap = tblH[(size_t)i * NPIX + ra];
  if (ap < 0) ap = 0; if (ap > NPIX - 1) ap = NPIX - 1;
  const uint4* A4 = (const uint4*)(PQ + (size_t)ap * 32);
  u32 rem = (u32)(q * 256 + t);
  u32 k20 = K.k2[i][0], k21 = K.k2[i][1];
  float Lr[7];
  #pragma unroll
  for (int j = 0; j < 7; j++) Lr[j] = simL[i * 8 + j];
  float mg = 0.f; int pick = 0;
  #pragma unroll
  for (int j = 0; j < 7; j++) {
    u32 bits = rbits(k20, k21, rem * 7u + (u32)j);
    float f = u01(bits);
    float u = fmaxf(f, 1.17549435e-38f);
    float g = -__logf(-__logf(u));
    float v = g + Lr[j];
    if (j == 0) { mg = v; } else if (v > mg) { mg = v; pick = j; }
  }
  int nc = (i + 1 + pick) & 7;
  u32 bits3 = rbits(K.k3[i][0], K.k3[i][1], rem);
  float u3 = u01(bits3);
  int cntv = counts[nc];
  int rn = (int)(u3 * (float)cntv);
  int cap2 = cntv - 1; if (cap2 < 0) cap2 = 0;
  if (rn > cap2) rn = cap2; if (rn < 0) rn = 0;
  int np = tblV[(size_t)nc * NPIX + rn];
  if (np < 0) np = 0; if (np > NPIX - 1) np = NPIX - 1;
  const uint4* B = (const uint4*)(PQ + (size_t)np * 32);
  float accN = 0.f;
  #pragma unroll
  for (int k = 0; k < 8; k++) {
    uint4 ua = A4[k], ub = B[k];
    float2 fa, fb; float d, dn;
    fa = unpackPQ(ua.x); fb = unpackPQ(ub.x); d = fa.x - fb.x; dn = fa.y + fb.y; accN += d * d * frcp(dn) + __logf(dn);
    fa = unpackPQ(ua.y); fb = unpackPQ(ub.y); d = fa.x - fb.x; dn = fa.y + fb.y; accN += d * d * frcp(dn) + __logf(dn);
    fa = unpackPQ(ua.z); fb = unpackPQ(ub.z); d = fa.x - fb.x; dn = fa.y + fb.y; accN += d * d * frcp(dn) + __logf(dn);
    fa = unpackPQ(ua.w); fb = unpackPQ(ub.w); d = fa.x - fb.x; dn = fa.y + fb.y; accN += d * d * frcp(dn) + __logf(dn);
  }
  float lN = -(accN * (1.0f / 32.0f));
  float l0 = 0.f;
  if (t == 0) {
    const uint4* B0 = (const uint4*)(protoPQ + i * 32);
    float acc0 = 0.f;
    #pragma unroll
    for (int k = 0; k < 8; k++) {
      uint4 ua = A4[k], ub = B0[k];
      float2 fa, fb; float d, dn;
      fa = unpackPQ(ua.x); fb = unpackPQ(ub.x); d = fa.x - fb.x; dn = fa.y + fb.y; acc0 += d * d * frcp(dn) + __logf(dn);
      fa = unpackPQ(ua.y); fb = unpackPQ(ub.y); d = fa.x - fb.x; dn = fa.y + fb.y; acc0 += d * d * frcp(dn) + __logf(dn);
      fa = unpackPQ(ua.z); fb = unpackPQ(ub.z); d = fa.x - fb.x; dn = fa.y + fb.y; acc0 += d * d * frcp(dn) + __logf(dn);
      fa = unpackPQ(ua.w); fb = unpackPQ(ub.w); d = fa.x - fb.x; dn = fa.y + fb.y; acc0 += d * d * frcp(dn) + __logf(dn);
    }
    l0 = -(acc0 * (1.0f / 32.0f));
  }
  bool bad = !(lN == lN) || (t == 0 && !(l0 == l0));
  if (__ballot(bad) != 0ull && (t & 63) == 0) atomicOr(diag, 8);
  float lm = (t == 0) ? fmaxf(lN, l0) : lN;
  #pragma unroll
  for (int d = 1; d < 64; d <<= 1) lm = fmaxf(lm, __shfl_xor(lm, d));
  if ((t & 63) == 0) redM[t >> 6] = lm;
  __syncthreads();
  float M = fmaxf(fmaxf(redM[0], redM[1]), fmaxf(redM[2], redM[3]));
  float es = __expf(lN - M) + ((t == 0) ? __expf(l0 - M) : 0.f);
  #pragma unroll
  for (int d = 1; d < 64; d <<= 1) es += __shfl_xor(es, d);
  if ((t & 63) == 0) redS[t >> 6] = es;
  __syncthreads();
  if (t == 0) {
    float S = redS[0] + redS[1] + redS[2] + redS[3];
    float ce = (M + __logf(S)) - l0;
    atomicAdd(&ceAcc[i], ce);
  }
  // ---- epilogue: k_final by the last-done block (R14-proven) ----
  __syncthreads();
  if (t == 0) {
    __threadfence();
    u32 done = (u32)atomicAdd(doneCnt, 1);
    if (done == 2047u) {
      int db = atomicOr(diag, 0);
      float loss = 0.f; int vn = 0;
      for (int ii = 0; ii < 8; ii++) {
        if (counts[ii] > 0) vn++;
        float ce = atomicAdd(&ceAcc[ii], 0.0f);    // coherent read
        if (counts[ii] > 0 && counts[8 + ii] > 0) {
          if (!(ce == ce)) db |= 4;
          loss += ce * (1.0f / 256.0f);
        }
      }
      if (vn == 0) db |= 1;
      loss = loss / (float)vn;
      if (!(loss == loss) && db == 0) db = 16;
      if (db != 0) loss = 4096.0f * (float)(1 + db);
      u32 fb = __float_as_uint(loss);
      u32 bv = (fb + 0x7FFFu + ((fb >> 16) & 1u)) >> 16;        // f32 -> bf16 RNE
      out[0] = (fb & 0xFFFF0000u) | (bv & 0xFFFFu);             // dual-decodable
    }
  }
}

// ---------------------------------------------------------------------------
extern "C" void kernel_launch(void* const* d_in, const int* in_sizes, int n_in,
                              void* d_out, int out_size, void* d_ws, size_t ws_size,
                              hipStream_t stream) {
  (void)in_sizes; (void)n_in; (void)out_size; (void)ws_size;
  const u16* wgt = (const u16*)d_in[0];
  const u16* mu  = (const u16*)d_in[1];
  const u16* sig = (const u16*)d_in[2];
  const u16* lab = (const u16*)d_in[3];
  const u16* msk = (const u16*)d_in[4];
  const u16* prb = (const u16*)d_in[5];

  // workspace carve (256B-aligned); total ~49 MB
  char* wp = (char*)d_ws;
  auto take = [&](size_t bytes) -> void* { void* p = (void*)wp; wp += ((bytes + 255) & ~(size_t)255); return p; };
  u32*   PQ       = (u32*)  take((size_t)NPIX * 32 * 4);
  int*   tblV     = (int*)  take((size_t)NCLS * NPIX * 4);
  int*   tblH     = (int*)  take((size_t)NCLS * NPIX * 4);
  unsigned char* flags = (unsigned char*)take(NPIX);
  int*   blockCnt = (int*)  take(16 * NBLK * 4);
  float* protoAcc = (float*)take(768 * 4);       // ---- memset region start ----
  u32*   protoPQ  = (u32*)  take(256 * 4);
  float* simL     = (float*)take(64 * 4);
  int*   counts   = (int*)  take(16 * 4);
  float* ceAcc    = (float*)take(8 * 4);
  int*   diag     = (int*)  take(4);
  int*   doneCnt  = (int*)  take(4);             // ---- memset region end ----
  size_t tailBytes = (size_t)(wp - (char*)protoAcc);

  // Host-side JAX key derivation (partitionable/fold-like split)
  TFKeys K;
  for (u32 i = 0; i < 8; i++) {
    u32 ki0, ki1;
    tf2x32(0u, 42u, 0u, i, ki0, ki1);
    tf2x32(ki0, ki1, 0u, 0u, K.k1[i][0], K.k1[i][1]);
    tf2x32(ki0, ki1, 0u, 1u, K.k2[i][0], K.k2[i][1]);
    tf2x32(ki0, ki1, 0u, 2u, K.k3[i][0], K.k3[i][1]);
  }

  hipMemsetAsync(protoAcc, 0, tailBytes, stream);
  k_pq_proto<<<512, 256, 0, stream>>>(mu, wgt, sig, lab, msk, prb, flags, blockCnt, PQ, protoAcc);
  k_place<<<1024, 256, 0, stream>>>(flags, blockCnt, tblV, tblH, counts, protoAcc, protoPQ, simL, diag);
  k_sample<<<2048, 256, 0, stream>>>(K, simL, counts, tblV, tblH, PQ, protoPQ, ceAcc, diag, doneCnt, (u32*)d_out);
}

// Round 13
// 221.234 us; speedup vs baseline: 1.1386x; 1.1386x over previous
//
#include <hip/hip_runtime.h>
#include <hip/hip_fp16.h>
#include <stdint.h>

// ============================================================================
// Mix_Loss on MI355X.  R22 = R21 resubmitted unchanged (Round 12 bench failed
// at container acquisition — no kernel execution, no counters).
//  R20 post-mortem: the k_final fold's EPILOGUE (threadfence x 2048 + global
//  done-counter) cost ~30us in k_sample (74 vs 42) — device-scope fences
//  drain cross-XCD L2 visibility per block. R14's +37 was THIS, not the
//  prologue. The other two folds are correct and net ~-5us.
//  R21/R22 = R20 minus k_final fold:
//   - k_pq_proto: verbatim R20 (flags fold + R18 tile/pacc body).
//   - k_place:    verbatim R20 (protoFinal tail in block 0).
//   - k_sample:   verbatim R11/R18 proven body (no fence/doneCnt).
//   - k_final:    separate 1-block launch (R18 proven).
// ============================================================================

#define NPIX  262144   // B*H*W = 4*256*256
#define NCLS  8
#define NQ    256
#define NNEG  256
#define NBLK  1024     // 256-pixel chunks for place

typedef unsigned short u16;
typedef unsigned int   u32;

struct TFKeys { u32 k1[8][2], k2[8][2], k3[8][2]; };

// JAX threefry2x32 (20 rounds)
__host__ __device__ inline void tf2x32(u32 k0, u32 k1, u32 x0, u32 x1, u32& o0, u32& o1) {
  u32 ks2 = k0 ^ k1 ^ 0x1BD11BDAu;
  x0 += k0; x1 += k1;
#define TFR(R) { x0 += x1; x1 = (x1 << (R)) | (x1 >> (32 - (R))); x1 ^= x0; }
  TFR(13) TFR(15) TFR(26) TFR(6)
  x0 += k1;  x1 += ks2 + 1u;
  TFR(17) TFR(29) TFR(16) TFR(24)
  x0 += ks2; x1 += k0 + 2u;
  TFR(13) TFR(15) TFR(26) TFR(6)
  x0 += k0;  x1 += k1 + 3u;
  TFR(17) TFR(29) TFR(16) TFR(24)
  x0 += k1;  x1 += ks2 + 4u;
  TFR(13) TFR(15) TFR(26) TFR(6)
  x0 += ks2; x1 += k0 + 5u;
#undef TFR
  o0 = x0; o1 = x1;
}

__device__ inline float bfv(u16 v) { return __uint_as_float(((u32)v) << 16); }
__device__ inline float lo16(u32 v) { return __uint_as_float(v << 16); }
__device__ inline float hi16(u32 v) { return __uint_as_float(v & 0xFFFF0000u); }
__device__ inline float u01(u32 bits) { return __uint_as_float((bits >> 9) | 0x3F800000u) - 1.0f; }
__device__ inline u32 rbits(u32 k0, u32 k1, u32 idx) { u32 a, b; tf2x32(k0, k1, 0u, idx, a, b); return a ^ b; }
__device__ inline u32 packPQ(float p, float q) {
  return (u32)__half_as_ushort(__float2half(p)) | ((u32)__half_as_ushort(__float2half(q)) << 16);
}
__device__ inline float2 unpackPQ(u32 v) {
  return make_float2(__half2float(__ushort_as_half((u16)(v & 0xFFFFu))),
                     __half2float(__ushort_as_half((u16)(v >> 16))));
}
__device__ inline float frcp(float x) { return __builtin_amdgcn_rcpf(x); }

// ---------------------------------------------------------------------------
// R20 k_pq_proto (proven): [flags fold, R2 logic bit-identical] + [R18 body:
// LDS transpose tile + 4-way replicated pacc]. Dual-column blockCnt write.
__global__ __launch_bounds__(256) void k_pq_proto(const u16* __restrict__ mu, const u16* __restrict__ wgt,
                                                  const u16* __restrict__ sig,
                                                  const u16* __restrict__ lab, const u16* __restrict__ msk,
                                                  const u16* __restrict__ prb,
                                                  unsigned char* __restrict__ flags,
                                                  int* __restrict__ blockCnt,
                                                  u32* __restrict__ PQ, float* __restrict__ protoAcc) {
  __shared__ u32 tile[256 * 33];
  __shared__ float pacc[4 * 808];
  __shared__ int cnt[32];
  int t = threadIdx.x;
  for (int i = t; i < 4 * 808; i += 256) pacc[i] = 0.f;
  if (t < 32) cnt[t] = 0;
  __syncthreads();
  int n0 = blockIdx.x * 512;
  int b = n0 >> 16;
  int hwt = (n0 & 65535) + 2 * t;
  size_t cb = ((size_t)(b * 32)) << 16;
  // ---- flags computation (logic verbatim R2 k_flags), 2 pixels ----
  u32 mk2 = *(const u32*)(msk + (((size_t)b) << 16) + hwt);
  float mk0 = lo16(mk2), mk1 = hi16(mk2);
  int cls0 = 0, cls1 = 0; bool v0 = false, v1 = false;
  for (int s = 0; s < 8; s++) {
    u32 l2 = *(const u32*)(lab + (((size_t)(b * 8 + s)) << 16) + hwt);
    if (lo16(l2) * mk0 > 0.f) { cls0 = s; v0 = true; }
    if (hi16(l2) * mk1 > 0.f) { cls1 = s; v1 = true; }
  }
  bool h0 = false, h1 = false;
  if (v0) { float p = bfv(prb[(((size_t)(b * 8 + cls0)) << 16) + hwt]);     h0 = p < 0.97f; }
  if (v1) { float p = bfv(prb[(((size_t)(b * 8 + cls1)) << 16) + hwt + 1]); h1 = p < 0.97f; }
  {
    int half16 = (t >> 7) * 16;
    if (v0) atomicAdd(&cnt[half16 + cls0], 1);
    if (h0) atomicAdd(&cnt[half16 + 8 + cls0], 1);
    if (v1) atomicAdd(&cnt[half16 + cls1], 1);
    if (h1) atomicAdd(&cnt[half16 + 8 + cls1], 1);
    u32 f0 = (u32)cls0 | (v0 ? 16u : 0u) | (h0 ? 32u : 0u);
    u32 f1 = (u32)cls1 | (v1 ? 16u : 0u) | (h1 ? 32u : 0u);
    *(u16*)(flags + n0 + 2 * t) = (u16)(f0 | (f1 << 8));
  }
  // ---- R18 pq + proto body (local cls/v) ----
  int copy = (t & 3) * 808;
  int base0 = copy + cls0 * 100, base1 = copy + cls1 * 100;
  u32 m2[32];
  float ss0 = 0.f, ss1 = 0.f;
  #pragma unroll
  for (int c = 0; c < 32; c++) {
    m2[c] = *(const u32*)(mu + cb + ((size_t)c << 16) + hwt);
    float a = lo16(m2[c]), d = hi16(m2[c]);
    ss0 += a * a; ss1 += d * d;
  }
  float rn0 = 1.0f / fmaxf(sqrtf(ss0), 1e-12f);
  float rn1 = 1.0f / fmaxf(sqrtf(ss1), 1e-12f);
  u32 pk0[32], pk1[32];
  #pragma unroll
  for (int c = 0; c < 32; c++) {
    u32 w2 = *(const u32*)(wgt + cb + ((size_t)c << 16) + hwt);
    u32 s2 = *(const u32*)(sig + cb + ((size_t)c << 16) + hwt);
    float wl = lo16(w2), wh = hi16(w2);
    float sl = lo16(s2), sh = hi16(s2);
    float ml = lo16(m2[c]), mh = hi16(m2[c]);
    pk0[c] = packPQ(ml * rn0 * wl, sl * wl);
    pk1[c] = packPQ(mh * rn1 * wh, sh * wh);
    if (v0) {
      float isw = wl / sl;                       // IEEE div (matches reference)
      atomicAdd(&pacc[base0 + c * 3 + 0], isw);
      atomicAdd(&pacc[base0 + c * 3 + 1], isw * ml);
      atomicAdd(&pacc[base0 + c * 3 + 2], 1.0f / wl);
    }
    if (v1) {
      float isw = wh / sh;
      atomicAdd(&pacc[base1 + c * 3 + 0], isw);
      atomicAdd(&pacc[base1 + c * 3 + 1], isw * mh);
      atomicAdd(&pacc[base1 + c * 3 + 2], 1.0f / wh);
    }
  }
  // PQ transpose + write (verbatim R8)
  #pragma unroll
  for (int ch = 0; ch < 2; ch++) {
    if ((t >> 7) == ch) {
      int l = t & 127;
      #pragma unroll
      for (int c = 0; c < 32; c++) {
        tile[(2 * l + 0) * 33 + c] = pk0[c];
        tile[(2 * l + 1) * 33 + c] = pk1[c];
      }
    }
    __syncthreads();
    uint4* dst = (uint4*)(PQ + (size_t)(n0 + ch * 256) * 32);
    for (int k = t; k < 2048; k += 256) {
      int p = k >> 3, c4 = (k & 7) * 4;
      dst[k] = make_uint4(tile[p * 33 + c4], tile[p * 33 + c4 + 1],
                          tile[p * 33 + c4 + 2], tile[p * 33 + c4 + 3]);
    }
    __syncthreads();
  }
  // flush pacc -> protoAcc (pre-reduce 4 copies; same 768 bins)
  for (int idx = t; idx < 800; idx += 256) {
    int c8 = idx / 100, rem = idx - c8 * 100;
    if (rem < 96) {
      float sum = pacc[idx] + pacc[idx + 808] + pacc[idx + 1616] + pacc[idx + 2424];
      atomicAdd(&protoAcc[c8 * 96 + rem], sum);
    }
  }
  // blockCnt dual-column write (covers 256-px chunks 2*bid and 2*bid+1)
  if (t < 32) blockCnt[(t & 15) * NBLK + 2 * blockIdx.x + (t >> 4)] = cnt[(t >> 4) * 16 + (t & 15)];
}

// ---------------------------------------------------------------------------
// k_place (R14-proven body) + protoFinal tail in block 0 (R20-proven).
__global__ __launch_bounds__(256) void k_place(const unsigned char* __restrict__ flags,
                                               const int* __restrict__ blockCnt,
                                               int* __restrict__ tblV, int* __restrict__ tblH,
                                               int* __restrict__ counts,
                                               const float* __restrict__ protoAcc,
                                               u32* __restrict__ protoPQ, float* __restrict__ simL,
                                               int* __restrict__ diag) {
  __shared__ int wcnt[4][16];
  __shared__ int sOff[16], sTot[16];
  __shared__ float sP[256], sQ[256];
  __shared__ int alive;
  int tid = threadIdx.x;
  int blk = blockIdx.x;
  if (tid < 16) { sOff[tid] = 0; sTot[tid] = 0; }
  __syncthreads();
  {
    int ctr = tid & 15, seg = tid >> 4;              // 16 segs x 64 entries
    const int* row = blockCnt + ctr * NBLK + seg * 64;
    int lim = blk - seg * 64;                        // j < blk  <=>  l < lim
    int pre = 0, tot = 0;
    #pragma unroll 8
    for (int l = 0; l < 64; ++l) {
      int v = row[l];
      tot += v;
      pre += (l < lim) ? v : 0;
    }
    atomicAdd(&sOff[ctr], pre);
    if (blk == 0) atomicAdd(&sTot[ctr], tot);
  }
  __syncthreads();
  if (blk == 0 && tid < 16) counts[tid] = sTot[tid];
  // ---------------- original place body ----------------
  int n = blk * 256 + tid;
  int f = flags[n];
  int cls = f & 15; bool v = (f & 16) != 0, h = (f & 32) != 0;
  int wave = tid >> 6, lane = tid & 63;
  unsigned long long below = (1ull << lane) - 1ull;
  int rv = 0, rh = 0;
  for (int s = 0; s < 8; s++) {
    unsigned long long bv = __ballot(v && (cls == s));
    unsigned long long bh = __ballot(h && (cls == s));
    if (lane == 0) { wcnt[wave][s] = __popcll(bv); wcnt[wave][8 + s] = __popcll(bh); }
    if (cls == s) { rv = __popcll(bv & below); rh = __popcll(bh & below); }
  }
  __syncthreads();
  int preV = 0, preH = 0;
  for (int w2 = 0; w2 < wave; w2++) { preV += wcnt[w2][cls]; preH += wcnt[w2][8 + cls]; }
  if (v) tblV[(size_t)cls * NPIX + sOff[cls] + preV + rv] = n;
  if (h) tblH[(size_t)cls * NPIX + sOff[8 + cls] + preH + rh] = n;
  // ---------------- protoFinal tail (block 0 only; R8 body) ----------------
  if (blk == 0) {
    if (tid == 0) alive = 0;
    float a0 = protoAcc[tid * 3 + 0], a1 = protoAcc[tid * 3 + 1], a2 = protoAcc[tid * 3 + 2];
    bool have = sTot[tid >> 5] > 0;
    bool ok = (a0 > 0.f) && (a2 > 0.f);
    __syncthreads();
    if (have && !ok) atomicOr(diag, 2);
    if (have && ok) alive = 1;
    float psig = 1.0f / a0;
    float pmu  = psig * a1;
    float pw   = 1.0f / a2;
    float sq = (have && ok) ? pmu * pmu : 0.f;
    #pragma unroll
    for (int d = 1; d < 32; d <<= 1) sq += __shfl_xor(sq, d);
    float rn = 1.0f / fmaxf(sqrtf(sq), 1e-12f);
    float pP = (have && ok) ? pmu * rn * pw : 0.f;
    float pQ = (have && ok) ? psig * pw : 0.f;
    sP[tid] = pP; sQ[tid] = pQ;
    protoPQ[tid] = packPQ(pP, pQ);
    __syncthreads();
    if (tid == 0 && alive == 0) atomicOr(diag, 32);
    if (tid < 64) {
      int i = tid >> 3, j = tid & 7;
      if (j < 7) {
        int o = (i + 1 + j) & 7;
        float acc = 0.f;
        for (int c = 0; c < 32; c++) {
          float d = sP[i * 32 + c] - sP[o * 32 + c];
          float dn = sQ[i * 32 + c] + sQ[o * 32 + c];
          acc += d * d / dn + logf(dn);
        }
        float sim = -0.5f * (acc * (1.0f / 32.0f));
        simL[i * 8 + j] = (sTot[o] > 0) ? (sim * 2.0f) : -INFINITY;  // /TEMP(0.5)
      }
    }
  }
}

// ---- R11/R18 k_sample (proven 42.0us): no fence, no doneCnt.
__global__ __launch_bounds__(256) void k_sample(TFKeys K, const float* __restrict__ simL,
                                                const int* __restrict__ counts,
                                                const int* __restrict__ tblV, const int* __restrict__ tblH,
                                                const u32* __restrict__ PQ, const u32* __restrict__ protoPQ,
                                                float* __restrict__ ceAcc, int* __restrict__ diag) {
  __shared__ float redM[4], redS[4];
  int blk = blockIdx.x;
  int i = blk >> 8, q = blk & 255;
  int t = threadIdx.x;
  u32 abits = rbits(K.k1[i][0], K.k1[i][1], (u32)q);
  float au = u01(abits);
  int hc = counts[8 + i];
  int ra = (int)(au * (float)hc);
  int cap = hc - 1; if (cap < 0) cap = 0;
  if (ra > cap) ra = cap; if (ra < 0) ra = 0;
  int ap = tblH[(size_t)i * NPIX + ra];
  if (ap < 0) ap = 0; if (ap > NPIX - 1) ap = NPIX - 1;
  const uint4* A4 = (const uint4*)(PQ + (size_t)ap * 32);
  u32 rem = (u32)(q * 256 + t);
  u32 k20 = K.k2[i][0], k21 = K.k2[i][1];
  float Lr[7];
  #pragma unroll
  for (int j = 0; j < 7; j++) Lr[j] = simL[i * 8 + j];
  float mg = 0.f; int pick = 0;
  #pragma unroll
  for (int j = 0; j < 7; j++) {
    u32 bits = rbits(k20, k21, rem * 7u + (u32)j);
    float f = u01(bits);
    float u = fmaxf(f, 1.17549435e-38f);
    float g = -__logf(-__logf(u));
    float v = g + Lr[j];
    if (j == 0) { mg = v; } else if (v > mg) { mg = v; pick = j; }
  }
  int nc = (i + 1 + pick) & 7;
  u32 bits3 = rbits(K.k3[i][0], K.k3[i][1], rem);
  float u3 = u01(bits3);
  int cntv = counts[nc];
  int rn = (int)(u3 * (float)cntv);
  int cap2 = cntv - 1; if (cap2 < 0) cap2 = 0;
  if (rn > cap2) rn = cap2; if (rn < 0) rn = 0;
  int np = tblV[(size_t)nc * NPIX + rn];
  if (np < 0) np = 0; if (np > NPIX - 1) np = NPIX - 1;
  const uint4* B = (const uint4*)(PQ + (size_t)np * 32);
  float accN = 0.f;
  #pragma unroll
  for (int k = 0; k < 8; k++) {
    uint4 ua = A4[k], ub = B[k];
    float2 fa, fb; float d, dn;
    fa = unpackPQ(ua.x); fb = unpackPQ(ub.x); d = fa.x - fb.x; dn = fa.y + fb.y; accN += d * d * frcp(dn) + __logf(dn);
    fa = unpackPQ(ua.y); fb = unpackPQ(ub.y); d = fa.x - fb.x; dn = fa.y + fb.y; accN += d * d * frcp(dn) + __logf(dn);
    fa = unpackPQ(ua.z); fb = unpackPQ(ub.z); d = fa.x - fb.x; dn = fa.y + fb.y; accN += d * d * frcp(dn) + __logf(dn);
    fa = unpackPQ(ua.w); fb = unpackPQ(ub.w); d = fa.x - fb.x; dn = fa.y + fb.y; accN += d * d * frcp(dn) + __logf(dn);
  }
  float lN = -(accN * (1.0f / 32.0f));
  float l0 = 0.f;
  if (t == 0) {
    const uint4* B0 = (const uint4*)(protoPQ + i * 32);
    float acc0 = 0.f;
    #pragma unroll
    for (int k = 0; k < 8; k++) {
      uint4 ua = A4[k], ub = B0[k];
      float2 fa, fb; float d, dn;
      fa = unpackPQ(ua.x); fb = unpackPQ(ub.x); d = fa.x - fb.x; dn = fa.y + fb.y; acc0 += d * d * frcp(dn) + __logf(dn);
      fa = unpackPQ(ua.y); fb = unpackPQ(ub.y); d = fa.x - fb.x; dn = fa.y + fb.y; acc0 += d * d * frcp(dn) + __logf(dn);
      fa = unpackPQ(ua.z); fb = unpackPQ(ub.z); d = fa.x - fb.x; dn = fa.y + fb.y; acc0 += d * d * frcp(dn) + __logf(dn);
      fa = unpackPQ(ua.w); fb = unpackPQ(ub.w); d = fa.x - fb.x; dn = fa.y + fb.y; acc0 += d * d * frcp(dn) + __logf(dn);
    }
    l0 = -(acc0 * (1.0f / 32.0f));
  }
  bool bad = !(lN == lN) || (t == 0 && !(l0 == l0));
  if (__ballot(bad) != 0ull && (t & 63) == 0) atomicOr(diag, 8);
  float lm = (t == 0) ? fmaxf(lN, l0) : lN;
  #pragma unroll
  for (int d = 1; d < 64; d <<= 1) lm = fmaxf(lm, __shfl_xor(lm, d));
  if ((t & 63) == 0) redM[t >> 6] = lm;
  __syncthreads();
  float M = fmaxf(fmaxf(redM[0], redM[1]), fmaxf(redM[2], redM[3]));
  float es = __expf(lN - M) + ((t == 0) ? __expf(l0 - M) : 0.f);
  #pragma unroll
  for (int d = 1; d < 64; d <<= 1) es += __shfl_xor(es, d);
  if ((t & 63) == 0) redS[t >> 6] = es;
  __syncthreads();
  if (t == 0) {
    float S = redS[0] + redS[1] + redS[2] + redS[3];
    float ce = (M + __logf(S)) - l0;
    atomicAdd(&ceAcc[i], ce);
  }
}

__global__ void k_final(const float* __restrict__ ceAcc, const int* __restrict__ counts,
                        const int* __restrict__ diag, u32* __restrict__ out) {
  if (blockIdx.x == 0 && threadIdx.x == 0) {
    float loss = 0.f; int vn = 0;
    int db = diag[0];
    for (int i = 0; i < 8; i++) {
      if (counts[i] > 0) vn++;
      float ce = ceAcc[i];
      if (counts[i] > 0 && counts[8 + i] > 0) {
        if (!(ce == ce)) db |= 4;
        loss += ce * (1.0f / 256.0f);
      }
    }
    if (vn == 0) db |= 1;
    loss = loss / (float)vn;
    if (!(loss == loss) && db == 0) db = 16;
    if (db != 0) loss = 4096.0f * (float)(1 + db);
    u32 fb = __float_as_uint(loss);
    u32 bv = (fb + 0x7FFFu + ((fb >> 16) & 1u)) >> 16;          // f32 -> bf16 RNE
    out[0] = (fb & 0xFFFF0000u) | (bv & 0xFFFFu);               // dual-decodable
  }
}

// ---------------------------------------------------------------------------
extern "C" void kernel_launch(void* const* d_in, const int* in_sizes, int n_in,
                              void* d_out, int out_size, void* d_ws, size_t ws_size,
                              hipStream_t stream) {
  (void)in_sizes; (void)n_in; (void)out_size; (void)ws_size;
  const u16* wgt = (const u16*)d_in[0];
  const u16* mu  = (const u16*)d_in[1];
  const u16* sig = (const u16*)d_in[2];
  const u16* lab = (const u16*)d_in[3];
  const u16* msk = (const u16*)d_in[4];
  const u16* prb = (const u16*)d_in[5];

  // workspace carve (256B-aligned); total ~49 MB
  char* wp = (char*)d_ws;
  auto take = [&](size_t bytes) -> void* { void* p = (void*)wp; wp += ((bytes + 255) & ~(size_t)255); return p; };
  u32*   PQ       = (u32*)  take((size_t)NPIX * 32 * 4);
  int*   tblV     = (int*)  take((size_t)NCLS * NPIX * 4);
  int*   tblH     = (int*)  take((size_t)NCLS * NPIX * 4);
  unsigned char* flags = (unsigned char*)take(NPIX);
  int*   blockCnt = (int*)  take(16 * NBLK * 4);
  float* protoAcc = (float*)take(768 * 4);       // ---- memset region start ----
  u32*   protoPQ  = (u32*)  take(256 * 4);
  float* simL     = (float*)take(64 * 4);
  int*   counts   = (int*)  take(16 * 4);
  float* ceAcc    = (float*)take(8 * 4);
  int*   diag     = (int*)  take(4);             // ---- memset region end ----
  size_t tailBytes = (size_t)(wp - (char*)protoAcc);

  // Host-side JAX key derivation (partitionable/fold-like split)
  TFKeys K;
  for (u32 i = 0; i < 8; i++) {
    u32 ki0, ki1;
    tf2x32(0u, 42u, 0u, i, ki0, ki1);
    tf2x32(ki0, ki1, 0u, 0u, K.k1[i][0], K.k1[i][1]);
    tf2x32(ki0, ki1, 0u, 1u, K.k2[i][0], K.k2[i][1]);
    tf2x32(ki0, ki1, 0u, 2u, K.k3[i][0], K.k3[i][1]);
  }

  hipMemsetAsync(protoAcc, 0, tailBytes, stream);
  k_pq_proto<<<512, 256, 0, stream>>>(mu, wgt, sig, lab, msk, prb, flags, blockCnt, PQ, protoAcc);
  k_place<<<1024, 256, 0, stream>>>(flags, blockCnt, tblV, tblH, counts, protoAcc, protoPQ, simL, diag);
  k_sample<<<2048, 256, 0, stream>>>(K, simL, counts, tblV, tblH, PQ, protoPQ, ceAcc, diag);
  k_final<<<1, 64, 0, stream>>>(ceAcc, counts, diag, (u32*)d_out);
}